// Round 1
// baseline (2412.550 us; speedup 1.0000x reference)
//
#include <hip/hip_runtime.h>
#include <hip/hip_bf16.h>
#include <math.h>

// ---------------------------------------------------------------------------
// QuantumEncoderLayer: B=32, S=512, d=512, H=4, hd=128, nq=8 (DIM=256), nl=4
// Round 1: correct fp32 implementation.
//   GEMM: 64x64 tile, BK=16, 256 thr, 4x4 microtile, LDS pad 68 (2-way = free)
//   Attention: block per (b,h,q-tile of 16), full score strip in LDS
//   Quantum: one wave per token; 256-amp state = 4 complex/lane in registers,
//            cross-lane gates via __shfl_xor. Fuses LN3 + angles + circuit +
//            expvals + qout projection + residual add.
// ---------------------------------------------------------------------------

__device__ __forceinline__ float waveAllSum(float v) {
#pragma unroll
  for (int m = 1; m < 64; m <<= 1) v += __shfl_xor(v, m, 64);
  return v;
}

// ---------------------------------------------------------------------------
// C[M,N] = A[M,K] @ W[N,K]^T + bias[N], optional exact GELU.
// M,N multiples of 64; K multiple of 16.
// ---------------------------------------------------------------------------
__global__ __launch_bounds__(256) void gemm_bias_kernel(
    const float* __restrict__ A, const float* __restrict__ W,
    const float* __restrict__ bias, float* __restrict__ C,
    int M, int N, int K, int apply_gelu) {
  __shared__ float As[16][68];
  __shared__ float Bs[16][68];
  int tid = threadIdx.x;
  int ty = tid >> 4, tx = tid & 15;
  long m0 = (long)blockIdx.x * 64;
  long n0 = (long)blockIdx.y * 64;
  const float* Ap = A + m0 * K;
  const float* Wp = W + n0 * K;
  float acc[4][4] = {};
  for (int k0 = 0; k0 < K; k0 += 16) {
#pragma unroll
    for (int r = 0; r < 4; ++r) {
      int e = tid + r * 256;
      int mm = e >> 4, kk = e & 15;
      As[kk][mm] = Ap[(long)mm * K + k0 + kk];
      Bs[kk][mm] = Wp[(long)mm * K + k0 + kk];
    }
    __syncthreads();
#pragma unroll
    for (int kk = 0; kk < 16; ++kk) {
      float4 a4 = *(const float4*)&As[kk][ty * 4];
      float4 b4 = *(const float4*)&Bs[kk][tx * 4];
      float av[4] = {a4.x, a4.y, a4.z, a4.w};
      float bv[4] = {b4.x, b4.y, b4.z, b4.w};
#pragma unroll
      for (int i = 0; i < 4; ++i)
#pragma unroll
        for (int j = 0; j < 4; ++j) acc[i][j] = fmaf(av[i], bv[j], acc[i][j]);
    }
    __syncthreads();
  }
#pragma unroll
  for (int i = 0; i < 4; ++i) {
    long row = m0 + ty * 4 + i;
#pragma unroll
    for (int j = 0; j < 4; ++j) {
      long col = n0 + tx * 4 + j;
      float v = acc[i][j] + bias[col];
      if (apply_gelu) v = 0.5f * v * (1.0f + erff(v * 0.70710678118654752f));
      C[row * N + col] = v;
    }
  }
}

// ---------------------------------------------------------------------------
// Attention. qkv layout (B,S,1536): q=[0,512), k=[512,1024), v=[1024,1536),
// head h occupies [h*128,(h+1)*128) within each third.
// Block: (b,h, 16 q-rows). o layout (B,S,512) with heads re-concatenated.
// ---------------------------------------------------------------------------
__global__ __launch_bounds__(256) void attn_kernel(const float* __restrict__ qkv,
                                                   float* __restrict__ o) {
  __shared__ float Qs[16][128];
  __shared__ float Ss[16][516];  // pad 516: softmax strided access ~2-way
  __shared__ float Ks[32][132];  // pad 132
  __shared__ float red[256];
  int tid = threadIdx.x;
  int bh = blockIdx.x;  // 0..127
  int b = bh >> 2, h = bh & 3;
  int q0 = blockIdx.y * 16;
  const float scale = 0.0883883476483184f;  // 1/sqrt(128)

  // load Q tile (scaled)
#pragma unroll
  for (int i = 0; i < 2; ++i) {
    int e4 = tid + i * 256;  // 512 float4
    int row = e4 >> 5;
    int c4 = (e4 & 31) * 4;
    const float* src =
        qkv + ((long)(b * 512 + q0 + row) * 1536) + h * 128 + c4;
    float4 v = *(const float4*)src;
    *(float4*)&Qs[row][c4] =
        make_float4(v.x * scale, v.y * scale, v.z * scale, v.w * scale);
  }
  __syncthreads();

  // Pass 1: scores
  for (int kt = 0; kt < 16; ++kt) {
#pragma unroll
    for (int i = 0; i < 4; ++i) {
      int e4 = tid + i * 256;  // 1024 float4
      int row = e4 >> 5;
      int c4 = (e4 & 31) * 4;
      const float* src =
          qkv + ((long)(b * 512 + kt * 32 + row) * 1536) + 512 + h * 128 + c4;
      *(float4*)&Ks[row][c4] = *(const float4*)src;
    }
    __syncthreads();
    int r = tid >> 4;
    int cb = tid & 15;
#pragma unroll
    for (int ci = 0; ci < 2; ++ci) {
      int cc = cb + ci * 16;
      float s = 0.f;
#pragma unroll 8
      for (int k = 0; k < 128; k += 4) {
        float4 q = *(const float4*)&Qs[r][k];
        float4 kv = *(const float4*)&Ks[cc][k];
        s = fmaf(q.x, kv.x, s);
        s = fmaf(q.y, kv.y, s);
        s = fmaf(q.z, kv.z, s);
        s = fmaf(q.w, kv.w, s);
      }
      Ss[r][kt * 32 + cc] = s;
    }
    __syncthreads();
  }

  // softmax over each of 16 rows (length 512); 16 threads/row, strided cols
  {
    int r = tid >> 4;
    int part = tid & 15;
    float m = -1e30f;
    for (int t = 0; t < 32; ++t) m = fmaxf(m, Ss[r][part + 16 * t]);
    red[tid] = m;
    __syncthreads();
    if (part == 0) {
      float mm = red[r * 16];
      for (int i = 1; i < 16; ++i) mm = fmaxf(mm, red[r * 16 + i]);
      red[r * 16] = mm;
    }
    __syncthreads();
    float rowmax = red[r * 16];
    float ssum = 0.f;
    for (int t = 0; t < 32; ++t) {
      int c = part + 16 * t;
      float e = expf(Ss[r][c] - rowmax);
      Ss[r][c] = e;
      ssum += e;
    }
    __syncthreads();
    red[tid] = ssum;
    __syncthreads();
    if (part == 0) {
      float s = 0.f;
      for (int i = 0; i < 16; ++i) s += red[r * 16 + i];
      red[r * 16] = s;
    }
    __syncthreads();
    float inv = 1.0f / red[r * 16];
    for (int t = 0; t < 32; ++t) Ss[r][part + 16 * t] *= inv;
    __syncthreads();
  }

  // Pass 2: O = P @ V
  float acc[8] = {};
  int r2 = tid >> 4;
  int c0 = (tid & 15) * 8;
  for (int kt = 0; kt < 16; ++kt) {
#pragma unroll
    for (int i = 0; i < 4; ++i) {
      int e4 = tid + i * 256;
      int row = e4 >> 5;
      int c4 = (e4 & 31) * 4;
      const float* src =
          qkv + ((long)(b * 512 + kt * 32 + row) * 1536) + 1024 + h * 128 + c4;
      *(float4*)&Ks[row][c4] = *(const float4*)src;
    }
    __syncthreads();
#pragma unroll 4
    for (int kk = 0; kk < 32; ++kk) {
      float p = Ss[r2][kt * 32 + kk];
      float4 v0 = *(const float4*)&Ks[kk][c0];
      float4 v1 = *(const float4*)&Ks[kk][c0 + 4];
      acc[0] = fmaf(p, v0.x, acc[0]);
      acc[1] = fmaf(p, v0.y, acc[1]);
      acc[2] = fmaf(p, v0.z, acc[2]);
      acc[3] = fmaf(p, v0.w, acc[3]);
      acc[4] = fmaf(p, v1.x, acc[4]);
      acc[5] = fmaf(p, v1.y, acc[5]);
      acc[6] = fmaf(p, v1.z, acc[6]);
      acc[7] = fmaf(p, v1.w, acc[7]);
    }
    __syncthreads();
  }
  float* dst = o + ((long)(b * 512 + q0 + r2) * 512) + h * 128 + c0;
  *(float4*)dst = make_float4(acc[0], acc[1], acc[2], acc[3]);
  *(float4*)(dst + 4) = make_float4(acc[4], acc[5], acc[6], acc[7]);
}

// ---------------------------------------------------------------------------
// out = LayerNorm(a + b) * g + be ; one wave per 512-row.
// Safe for out == b (each element read once by its own thread before write).
// ---------------------------------------------------------------------------
__global__ __launch_bounds__(256) void add_ln_kernel(
    const float* __restrict__ a, const float* __restrict__ b,
    const float* __restrict__ g, const float* __restrict__ be,
    float* __restrict__ out) {
  long row = (blockIdx.x * 256 + threadIdx.x) >> 6;
  int lane = threadIdx.x & 63;
  const float* ar = a + row * 512;
  const float* br = b + row * 512;
  float v[8];
  float s = 0.f;
#pragma unroll
  for (int j = 0; j < 8; ++j) {
    int c = lane + 64 * j;
    v[j] = ar[c] + br[c];
    s += v[j];
  }
  s = waveAllSum(s);
  float mean = s * (1.0f / 512.0f);
  float var = 0.f;
#pragma unroll
  for (int j = 0; j < 8; ++j) {
    float d = v[j] - mean;
    var = fmaf(d, d, var);
  }
  var = waveAllSum(var);
  float rstd = rsqrtf(var * (1.0f / 512.0f) + 1e-5f);
  float* orow = out + row * 512;
#pragma unroll
  for (int j = 0; j < 8; ++j) {
    int c = lane + 64 * j;
    orow[c] = (v[j] - mean) * rstd * g[c] + be[c];
  }
}

// ---------------------------------------------------------------------------
// Quantum stage, one wave per token row:
//   xn = LN(x1; g3,b3); ang = xn @ qin_w^T + qin_b;
//   z = expvals(circuit(ang, qw)); x2 = x1 + z @ qout_w^T + qout_b
// State: 256 complex amps; amp idx = lane*4 + l. Wire w <-> bit (7-w).
// Bits 0,1 intra-lane; bits 2..7 = lane bits 0..5 (shfl_xor).
// ---------------------------------------------------------------------------
__global__ __launch_bounds__(256) void quantum_kernel(
    const float* __restrict__ x1, const float* __restrict__ g3,
    const float* __restrict__ b3, const float* __restrict__ qin_w,
    const float* __restrict__ qin_b, const float* __restrict__ qw,
    const float* __restrict__ qout_w, const float* __restrict__ qout_b,
    float* __restrict__ x2) {
  long row = (blockIdx.x * 256 + threadIdx.x) >> 6;
  int lane = threadIdx.x & 63;
  const float* xr = x1 + row * 512;

  float xv[8], xn[8];
  float s = 0.f;
#pragma unroll
  for (int j = 0; j < 8; ++j) {
    xv[j] = xr[lane + 64 * j];
    s += xv[j];
  }
  s = waveAllSum(s);
  float mean = s * (1.0f / 512.0f);
  float var = 0.f;
#pragma unroll
  for (int j = 0; j < 8; ++j) {
    float d = xv[j] - mean;
    var = fmaf(d, d, var);
  }
  var = waveAllSum(var);
  float rstd = rsqrtf(var * (1.0f / 512.0f) + 1e-5f);
#pragma unroll
  for (int j = 0; j < 8; ++j) {
    int c = lane + 64 * j;
    xn[j] = (xv[j] - mean) * rstd * g3[c] + b3[c];
  }

  float ang[8];
#pragma unroll
  for (int w = 0; w < 8; ++w) {
    float p = 0.f;
#pragma unroll
    for (int j = 0; j < 8; ++j)
      p = fmaf(xn[j], qin_w[w * 512 + lane + 64 * j], p);
    p = waveAllSum(p);
    ang[w] = p + qin_b[w];
  }

  float sr[4], si[4];
  sr[0] = (lane == 0) ? 1.0f : 0.0f;
  sr[1] = sr[2] = sr[3] = 0.0f;
  si[0] = si[1] = si[2] = si[3] = 0.0f;

  auto rx = [&](int p, float c, float sn) {
    if (p >= 2) {
      int m = 1 << (p - 2);
#pragma unroll
      for (int l = 0; l < 4; ++l) {
        float pr = __shfl_xor(sr[l], m, 64);
        float pi = __shfl_xor(si[l], m, 64);
        float nr = fmaf(sn, pi, c * sr[l]);
        float ni = fmaf(-sn, pr, c * si[l]);
        sr[l] = nr;
        si[l] = ni;
      }
    } else {
      float nr[4], ni[4];
#pragma unroll
      for (int l = 0; l < 4; ++l) {
        int pl = l ^ (1 << p);
        nr[l] = fmaf(sn, si[pl], c * sr[l]);
        ni[l] = fmaf(-sn, sr[pl], c * si[l]);
      }
#pragma unroll
      for (int l = 0; l < 4; ++l) {
        sr[l] = nr[l];
        si[l] = ni[l];
      }
    }
  };
  auto rz = [&](int p, float c, float sn) {
#pragma unroll
    for (int l = 0; l < 4; ++l) {
      int bit = (p >= 2) ? ((lane >> (p - 2)) & 1) : ((l >> p) & 1);
      float sg = bit ? -sn : sn;
      float nr = fmaf(si[l], sg, sr[l] * c);
      float ni = fmaf(-sr[l], sg, si[l] * c);
      sr[l] = nr;
      si[l] = ni;
    }
  };
  auto docnot = [&](int i) {
    int pc = 7 - i, pt = 6 - i;
    if (pt >= 2) {
      int ctrl = (lane >> (pc - 2)) & 1;
      int m = 1 << (pt - 2);
#pragma unroll
      for (int l = 0; l < 4; ++l) {
        float pr = __shfl_xor(sr[l], m, 64);
        float pi = __shfl_xor(si[l], m, 64);
        if (ctrl) {
          sr[l] = pr;
          si[l] = pi;
        }
      }
    } else if (pt == 1) {  // pc==2: ctrl = lane bit0; swap locals 0<->2, 1<->3
      if (lane & 1) {
        float t;
        t = sr[0]; sr[0] = sr[2]; sr[2] = t;
        t = si[0]; si[0] = si[2]; si[2] = t;
        t = sr[1]; sr[1] = sr[3]; sr[3] = t;
        t = si[1]; si[1] = si[3]; si[3] = t;
      }
    } else {  // pc==1, pt==0: ctrl = local bit1; swap locals 2<->3
      float t;
      t = sr[2]; sr[2] = sr[3]; sr[3] = t;
      t = si[2]; si[2] = si[3]; si[3] = t;
    }
  };

  // encoding: RX(ang[i]) then RZ(ang[i]) on wire i
#pragma unroll
  for (int i = 0; i < 8; ++i) {
    float half = ang[i] * 0.5f;
    float c, sn;
    sincosf(half, &sn, &c);
    rx(7 - i, c, sn);
    rz(7 - i, c, sn);
  }
  // layers
#pragma unroll
  for (int l = 0; l < 4; ++l) {
#pragma unroll
    for (int i = 0; i < 8; ++i) {
      float aX = qw[l * 16 + i] * 0.5f;
      float cX, sX;
      sincosf(aX, &sX, &cX);
      rx(7 - i, cX, sX);
      float aZ = qw[l * 16 + 8 + i] * 0.5f;
      float cZ, sZ;
      sincosf(aZ, &sZ, &cZ);
      rz(7 - i, cZ, sZ);
    }
#pragma unroll
    for (int i = 0; i < 7; ++i) docnot(i);
  }

  // expectation values
  float pr4[4];
#pragma unroll
  for (int l = 0; l < 4; ++l) pr4[l] = sr[l] * sr[l] + si[l] * si[l];
  float z[8];
#pragma unroll
  for (int w = 0; w < 8; ++w) {
    int p = 7 - w;
    float part = 0.f;
#pragma unroll
    for (int l = 0; l < 4; ++l) {
      int bit = (p >= 2) ? ((lane >> (p - 2)) & 1) : ((l >> p) & 1);
      part += bit ? -pr4[l] : pr4[l];
    }
    z[w] = waveAllSum(part);
  }

  // x2 = x1 + z @ qout_w^T + qout_b
  float* orow = x2 + row * 512;
#pragma unroll
  for (int j = 0; j < 8; ++j) {
    int col = lane + 64 * j;
    float acc = qout_b[col];
#pragma unroll
    for (int w = 0; w < 8; ++w) acc = fmaf(z[w], qout_w[col * 8 + w], acc);
    orow[col] = xv[j] + acc;
  }
}

// ---------------------------------------------------------------------------
extern "C" void kernel_launch(void* const* d_in, const int* in_sizes, int n_in,
                              void* d_out, int out_size, void* d_ws,
                              size_t ws_size, hipStream_t stream) {
  const float* x = (const float*)d_in[0];
  const float* attn_in_w = (const float*)d_in[1];
  const float* attn_in_b = (const float*)d_in[2];
  const float* attn_out_w = (const float*)d_in[3];
  const float* attn_out_b = (const float*)d_in[4];
  const float* ln1_g = (const float*)d_in[5];
  const float* ln1_b = (const float*)d_in[6];
  const float* ln2_g = (const float*)d_in[7];
  const float* ln2_b = (const float*)d_in[8];
  const float* ln3_g = (const float*)d_in[9];
  const float* ln3_b = (const float*)d_in[10];
  const float* qin_w = (const float*)d_in[11];
  const float* qin_b = (const float*)d_in[12];
  const float* qweights = (const float*)d_in[13];
  const float* qout_w = (const float*)d_in[14];
  const float* qout_b = (const float*)d_in[15];
  const float* ffn_w1 = (const float*)d_in[16];
  const float* ffn_b1 = (const float*)d_in[17];
  const float* ffn_w2 = (const float*)d_in[18];
  const float* ffn_b2 = (const float*)d_in[19];

  const long E = 8388608L;  // 32*512*512
  float* ws = (float*)d_ws;
  float* qkv = ws;            // [0, 3E)
  float* obuf = ws + 3 * E;   // [3E, 4E)
  float* hbuf = ws;           // [0, 4E) reused after attention
  float* slot1 = ws + 4 * E;  // attn_out -> x1 (in-place LN) -> ffn_out
  float* x2 = ws + 5 * E;     // [5E, 6E)
  float* outp = (float*)d_out;

  const int M = 16384;  // B*S

  // 1. QKV projection
  gemm_bias_kernel<<<dim3(M / 64, 1536 / 64), 256, 0, stream>>>(
      x, attn_in_w, attn_in_b, qkv, M, 1536, 512, 0);
  // 2. attention
  attn_kernel<<<dim3(128, 32), 256, 0, stream>>>(qkv, obuf);
  // 3. output projection
  gemm_bias_kernel<<<dim3(M / 64, 512 / 64), 256, 0, stream>>>(
      obuf, attn_out_w, attn_out_b, slot1, M, 512, 512, 0);
  // 4. x1 = LN1(x + attn_out)  (in-place into slot1)
  add_ln_kernel<<<dim3(M / 4), 256, 0, stream>>>(x, slot1, ln1_g, ln1_b,
                                                 slot1);
  // 5. x2 = x1 + quantum(LN3(x1))
  quantum_kernel<<<dim3(M / 4), 256, 0, stream>>>(
      slot1, ln3_g, ln3_b, qin_w, qin_b, qweights, qout_w, qout_b, x2);
  // 6. h = gelu(x2 @ ffn_w1^T + b1)
  gemm_bias_kernel<<<dim3(M / 64, 2048 / 64), 256, 0, stream>>>(
      x2, ffn_w1, ffn_b1, hbuf, M, 2048, 512, 1);
  // 7. ffn_out = h @ ffn_w2^T + b2
  gemm_bias_kernel<<<dim3(M / 64, 512 / 64), 256, 0, stream>>>(
      hbuf, ffn_w2, ffn_b2, slot1, M, 512, 2048, 0);
  // 8. out = LN2(x2 + ffn_out)
  add_ln_kernel<<<dim3(M / 4), 256, 0, stream>>>(x2, slot1, ln2_g, ln2_b,
                                                 outp);
}

// Round 2
// 536.529 us; speedup vs baseline: 4.4966x; 4.4966x over previous
//
#include <hip/hip_runtime.h>
#include <math.h>

// ---------------------------------------------------------------------------
// QuantumEncoderLayer R2: bf16 MFMA everywhere.
//   B=32,S=512,d=512,H=4,hd=128, M=B*S=16384.
//   gemm_mfma: 128x128 tile, BK=32, global_load_lds(16B), 16x16x32 bf16 MFMA.
//     modes: 0 = f32 out; 1 = bf16 out + exact GELU; 2 = qkv-split
//     (q,k -> qk bf16 (B,S,1024); v -> vT bf16 (B,H,128,512) transposed so the
//      attention PV B-frags are contiguous ds_read_b128).
//   attn_mfma: flash-style, wave = 16 q rows, Bc=64, online softmax,
//     P->LDS round-trip (C-layout -> A-layout).
//   quantum/add_ln kernels: unchanged from R1 (verified), quantum dual-writes
//     fp32 + bf16 x2 for the FFN1 A-operand.
// ---------------------------------------------------------------------------

typedef __bf16 bf16;
typedef bf16 bf16x8 __attribute__((ext_vector_type(8)));
typedef bf16 bf16x4 __attribute__((ext_vector_type(4)));
typedef float f32x4 __attribute__((ext_vector_type(4)));

__device__ __forceinline__ void gld16(const void* g, void* l) {
  __builtin_amdgcn_global_load_lds(
      (__attribute__((address_space(1))) void*)(void*)g,
      (__attribute__((address_space(3))) void*)l, 16, 0, 0);
}

__device__ __forceinline__ float waveAllSum(float v) {
#pragma unroll
  for (int m = 1; m < 64; m <<= 1) v += __shfl_xor(v, m, 64);
  return v;
}

// ---------------------------------------------------------------------------
__global__ __launch_bounds__(256) void cvt_f32_bf16(
    const float* __restrict__ in, bf16* __restrict__ out, int n4) {
  int i = blockIdx.x * 256 + threadIdx.x;
  if (i >= n4) return;
  float4 v = ((const float4*)in)[i];
  bf16x4 o = {(bf16)v.x, (bf16)v.y, (bf16)v.z, (bf16)v.w};
  ((bf16x4*)out)[i] = o;
}

// ---------------------------------------------------------------------------
// C[M,N] = A[M,K] @ W[N,K]^T + bias.  A,W bf16 row-major.  M,N mult of 128,
// K mult of 32.
// ---------------------------------------------------------------------------
__global__ __launch_bounds__(256) void gemm_mfma(
    const bf16* __restrict__ A, const bf16* __restrict__ W,
    const float* __restrict__ bias, float* __restrict__ Cf,
    bf16* __restrict__ Cb, bf16* __restrict__ qk, bf16* __restrict__ vT,
    int M, int N, int K, int mode) {
  __shared__ __align__(16) bf16 As[128 * 32];
  __shared__ __align__(16) bf16 Bs[128 * 32];
  int tid = threadIdx.x;
  int lane = tid & 63, w = tid >> 6;
  int wr = w >> 1, wc = w & 1;
  int quad = lane >> 4, lc = lane & 15;
  long m0 = (long)blockIdx.x * 128;
  long n0 = (long)blockIdx.y * 128;
  int r4 = lane >> 2;            // 0..15: row within 16-row staging chunk
  int koff = (lane & 3) * 8;     // 4 lanes per 32-elem row
  f32x4 acc[4][4] = {};

  for (int k0 = 0; k0 < K; k0 += 32) {
    __syncthreads();
#pragma unroll
    for (int p = 0; p < 2; ++p) {
      int row = p * 64 + w * 16 + r4;
      gld16(A + (m0 + row) * (long)K + k0 + koff, &As[row * 32 + koff]);
      gld16(W + (n0 + row) * (long)K + k0 + koff, &Bs[row * 32 + koff]);
    }
    __syncthreads();
    bf16x8 af[4], bfr[4];
#pragma unroll
    for (int i = 0; i < 4; ++i) {
      af[i] = *(const bf16x8*)&As[(wr * 64 + i * 16 + lc) * 32 + quad * 8];
      bfr[i] = *(const bf16x8*)&Bs[(wc * 64 + i * 16 + lc) * 32 + quad * 8];
    }
#pragma unroll
    for (int i = 0; i < 4; ++i)
#pragma unroll
      for (int j = 0; j < 4; ++j)
        acc[i][j] = __builtin_amdgcn_mfma_f32_16x16x32_bf16(af[i], bfr[j],
                                                            acc[i][j], 0, 0, 0);
  }

#pragma unroll
  for (int i = 0; i < 4; ++i) {
    long grow0 = m0 + wr * 64 + i * 16 + quad * 4;
#pragma unroll
    for (int j = 0; j < 4; ++j) {
      long col = n0 + wc * 64 + j * 16 + lc;
      float bv = bias[col];
      float v[4];
#pragma unroll
      for (int r = 0; r < 4; ++r) v[r] = acc[i][j][r] + bv;
      if (mode == 0) {
#pragma unroll
        for (int r = 0; r < 4; ++r) Cf[(grow0 + r) * N + col] = v[r];
      } else if (mode == 1) {
#pragma unroll
        for (int r = 0; r < 4; ++r) {
          float g = 0.5f * v[r] * (1.0f + erff(v[r] * 0.70710678118654752f));
          Cb[(grow0 + r) * N + col] = (bf16)g;
        }
      } else {
        if (col < 1024) {
#pragma unroll
          for (int r = 0; r < 4; ++r) qk[(grow0 + r) * 1024 + col] = (bf16)v[r];
        } else {
          int hh = (int)((col - 1024) >> 7);
          int dd = (int)((col - 1024) & 127);
          long bidx = grow0 >> 9;
          int s0 = (int)(grow0 & 511);
          bf16x4 pk = {(bf16)v[0], (bf16)v[1], (bf16)v[2], (bf16)v[3]};
          *(bf16x4*)&vT[(((bidx << 2) + hh) * 128 + dd) * 512 + s0] = pk;
        }
      }
    }
  }
}

// ---------------------------------------------------------------------------
// Flash attention. qk (B,S,1024) bf16: q=[0,512), k=[512,1024) per row.
// vT (B,H,128,512) bf16. o (B,S,512) bf16 head-concat.
// Block: (b,h) x 64 q rows (wave w -> 16 rows). Bc=64.
// ---------------------------------------------------------------------------
__global__ __launch_bounds__(256) void attn_mfma(const bf16* __restrict__ qk,
                                                 const bf16* __restrict__ vT,
                                                 bf16* __restrict__ o) {
  __shared__ __align__(16) bf16 Ks[64 * 128];
  __shared__ __align__(16) bf16 Vt[128 * 64];
  __shared__ __align__(16) bf16 Ps[4][64 * 16];
  int tid = threadIdx.x, lane = tid & 63, w = tid >> 6;
  int quad = lane >> 4, lc = lane & 15;
  int bh = blockIdx.x, b = bh >> 2, h = bh & 3;
  int q0 = blockIdx.y * 64 + w * 16;
  const float scale = 0.08838834764831845f;  // 1/sqrt(128)

  bf16x8 qf[4];
  {
    const bf16* qp =
        qk + ((long)(b * 512 + q0 + lc)) * 1024 + h * 128 + quad * 8;
#pragma unroll
    for (int ks = 0; ks < 4; ++ks) qf[ks] = *(const bf16x8*)(qp + ks * 32);
  }
  f32x4 oacc[8] = {};
  float mrun[4] = {-1e30f, -1e30f, -1e30f, -1e30f};
  float lrun[4] = {0.f, 0.f, 0.f, 0.f};

  const bf16* kbase = qk + (long)b * 512 * 1024 + 512 + h * 128;
  const bf16* vbase = vT + (long)bh * 128 * 512;
  int kr = lane >> 4, ke = (lane & 15) * 8;   // K staging: 4 rows/call
  int vr = lane >> 3, ve = (lane & 7) * 8;    // V staging: 8 rows/call

  for (int kt = 0; kt < 512; kt += 64) {
    __syncthreads();
#pragma unroll
    for (int c = 0; c < 4; ++c) {
      int row = w * 16 + c * 4 + kr;
      gld16(kbase + (long)(kt + row) * 1024 + ke, &Ks[row * 128 + ke]);
    }
#pragma unroll
    for (int c = 0; c < 4; ++c) {
      int row = w * 32 + c * 8 + vr;
      gld16(vbase + (long)row * 512 + kt + ve, &Vt[row * 64 + ve]);
    }
    __syncthreads();

    // scores: 4 col-subtiles of 16
    float p[4][4];
#pragma unroll
    for (int c = 0; c < 4; ++c) {
      f32x4 a = {};
#pragma unroll
      for (int ks = 0; ks < 4; ++ks) {
        bf16x8 kf = *(const bf16x8*)&Ks[(c * 16 + lc) * 128 + ks * 32 + quad * 8];
        a = __builtin_amdgcn_mfma_f32_16x16x32_bf16(qf[ks], kf, a, 0, 0, 0);
      }
#pragma unroll
      for (int r = 0; r < 4; ++r) p[c][r] = a[r] * scale;
    }

    // online softmax (rows = quad*4 + r)
    float alpha[4];
#pragma unroll
    for (int r = 0; r < 4; ++r) {
      float mx = fmaxf(fmaxf(p[0][r], p[1][r]), fmaxf(p[2][r], p[3][r]));
#pragma unroll
      for (int m = 1; m < 16; m <<= 1) mx = fmaxf(mx, __shfl_xor(mx, m, 64));
      float mn = fmaxf(mrun[r], mx);
      alpha[r] = expf(mrun[r] - mn);
      mrun[r] = mn;
      float rs = 0.f;
#pragma unroll
      for (int c = 0; c < 4; ++c) {
        float e = expf(p[c][r] - mn);
        p[c][r] = e;
        rs += e;
      }
#pragma unroll
      for (int m = 1; m < 16; m <<= 1) rs += __shfl_xor(rs, m, 64);
      lrun[r] = lrun[r] * alpha[r] + rs;
    }
#pragma unroll
    for (int n = 0; n < 8; ++n)
#pragma unroll
      for (int r = 0; r < 4; ++r) oacc[n][r] *= alpha[r];

    // P (C-layout) -> LDS transposed [k][m] -> A-frags
#pragma unroll
    for (int c = 0; c < 4; ++c) {
      bf16x4 pk = {(bf16)p[c][0], (bf16)p[c][1], (bf16)p[c][2], (bf16)p[c][3]};
      *(bf16x4*)&Ps[w][(c * 16 + lc) * 16 + quad * 4] = pk;
    }
    bf16x8 pf[2];
#pragma unroll
    for (int kc = 0; kc < 2; ++kc) {
      bf16x8 t;
#pragma unroll
      for (int jj = 0; jj < 8; ++jj)
        t[jj] = Ps[w][(kc * 32 + quad * 8 + jj) * 16 + lc];
      pf[kc] = t;
    }
    // PV
#pragma unroll
    for (int n = 0; n < 8; ++n)
#pragma unroll
      for (int kc = 0; kc < 2; ++kc) {
        bf16x8 vf = *(const bf16x8*)&Vt[(n * 16 + lc) * 64 + kc * 32 + quad * 8];
        oacc[n] =
            __builtin_amdgcn_mfma_f32_16x16x32_bf16(pf[kc], vf, oacc[n], 0, 0, 0);
      }
  }

  float linv[4];
#pragma unroll
  for (int r = 0; r < 4; ++r) linv[r] = 1.0f / lrun[r];
  bf16* op = o + ((long)(b * 512 + q0 + quad * 4)) * 512 + h * 128 + lc;
#pragma unroll
  for (int n = 0; n < 8; ++n)
#pragma unroll
    for (int r = 0; r < 4; ++r)
      op[(long)r * 512 + n * 16] = (bf16)(oacc[n][r] * linv[r]);
}

// ---------------------------------------------------------------------------
__global__ __launch_bounds__(256) void add_ln_kernel(
    const float* __restrict__ a, const float* __restrict__ b,
    const float* __restrict__ g, const float* __restrict__ be,
    float* __restrict__ out) {
  long row = (blockIdx.x * 256 + threadIdx.x) >> 6;
  int lane = threadIdx.x & 63;
  const float* ar = a + row * 512;
  const float* br = b + row * 512;
  float v[8];
  float s = 0.f;
#pragma unroll
  for (int j = 0; j < 8; ++j) {
    int c = lane + 64 * j;
    v[j] = ar[c] + br[c];
    s += v[j];
  }
  s = waveAllSum(s);
  float mean = s * (1.0f / 512.0f);
  float var = 0.f;
#pragma unroll
  for (int j = 0; j < 8; ++j) {
    float d = v[j] - mean;
    var = fmaf(d, d, var);
  }
  var = waveAllSum(var);
  float rstd = rsqrtf(var * (1.0f / 512.0f) + 1e-5f);
  float* orow = out + row * 512;
#pragma unroll
  for (int j = 0; j < 8; ++j) {
    int c = lane + 64 * j;
    orow[c] = (v[j] - mean) * rstd * g[c] + be[c];
  }
}

// ---------------------------------------------------------------------------
__global__ __launch_bounds__(256) void quantum_kernel(
    const float* __restrict__ x1, const float* __restrict__ g3,
    const float* __restrict__ b3, const float* __restrict__ qin_w,
    const float* __restrict__ qin_b, const float* __restrict__ qw,
    const float* __restrict__ qout_w, const float* __restrict__ qout_b,
    float* __restrict__ x2, bf16* __restrict__ x2b) {
  long row = (blockIdx.x * 256 + threadIdx.x) >> 6;
  int lane = threadIdx.x & 63;
  const float* xr = x1 + row * 512;

  float xv[8], xn[8];
  float s = 0.f;
#pragma unroll
  for (int j = 0; j < 8; ++j) {
    xv[j] = xr[lane + 64 * j];
    s += xv[j];
  }
  s = waveAllSum(s);
  float mean = s * (1.0f / 512.0f);
  float var = 0.f;
#pragma unroll
  for (int j = 0; j < 8; ++j) {
    float d = xv[j] - mean;
    var = fmaf(d, d, var);
  }
  var = waveAllSum(var);
  float rstd = rsqrtf(var * (1.0f / 512.0f) + 1e-5f);
#pragma unroll
  for (int j = 0; j < 8; ++j) {
    int c = lane + 64 * j;
    xn[j] = (xv[j] - mean) * rstd * g3[c] + b3[c];
  }

  float ang[8];
#pragma unroll
  for (int w = 0; w < 8; ++w) {
    float p = 0.f;
#pragma unroll
    for (int j = 0; j < 8; ++j)
      p = fmaf(xn[j], qin_w[w * 512 + lane + 64 * j], p);
    p = waveAllSum(p);
    ang[w] = p + qin_b[w];
  }

  float sr[4], si[4];
  sr[0] = (lane == 0) ? 1.0f : 0.0f;
  sr[1] = sr[2] = sr[3] = 0.0f;
  si[0] = si[1] = si[2] = si[3] = 0.0f;

  auto rx = [&](int p, float c, float sn) {
    if (p >= 2) {
      int m = 1 << (p - 2);
#pragma unroll
      for (int l = 0; l < 4; ++l) {
        float pr = __shfl_xor(sr[l], m, 64);
        float pi = __shfl_xor(si[l], m, 64);
        float nr = fmaf(sn, pi, c * sr[l]);
        float ni = fmaf(-sn, pr, c * si[l]);
        sr[l] = nr;
        si[l] = ni;
      }
    } else {
      float nr[4], ni[4];
#pragma unroll
      for (int l = 0; l < 4; ++l) {
        int pl = l ^ (1 << p);
        nr[l] = fmaf(sn, si[pl], c * sr[l]);
        ni[l] = fmaf(-sn, sr[pl], c * si[l]);
      }
#pragma unroll
      for (int l = 0; l < 4; ++l) {
        sr[l] = nr[l];
        si[l] = ni[l];
      }
    }
  };
  auto rz = [&](int p, float c, float sn) {
#pragma unroll
    for (int l = 0; l < 4; ++l) {
      int bit = (p >= 2) ? ((lane >> (p - 2)) & 1) : ((l >> p) & 1);
      float sg = bit ? -sn : sn;
      float nr = fmaf(si[l], sg, sr[l] * c);
      float ni = fmaf(-sr[l], sg, si[l] * c);
      sr[l] = nr;
      si[l] = ni;
    }
  };
  auto docnot = [&](int i) {
    int pc = 7 - i, pt = 6 - i;
    if (pt >= 2) {
      int ctrl = (lane >> (pc - 2)) & 1;
      int m = 1 << (pt - 2);
#pragma unroll
      for (int l = 0; l < 4; ++l) {
        float pr = __shfl_xor(sr[l], m, 64);
        float pi = __shfl_xor(si[l], m, 64);
        if (ctrl) {
          sr[l] = pr;
          si[l] = pi;
        }
      }
    } else if (pt == 1) {
      if (lane & 1) {
        float t;
        t = sr[0]; sr[0] = sr[2]; sr[2] = t;
        t = si[0]; si[0] = si[2]; si[2] = t;
        t = sr[1]; sr[1] = sr[3]; sr[3] = t;
        t = si[1]; si[1] = si[3]; si[3] = t;
      }
    } else {
      float t;
      t = sr[2]; sr[2] = sr[3]; sr[3] = t;
      t = si[2]; si[2] = si[3]; si[3] = t;
    }
  };

#pragma unroll
  for (int i = 0; i < 8; ++i) {
    float half = ang[i] * 0.5f;
    float c, sn;
    sincosf(half, &sn, &c);
    rx(7 - i, c, sn);
    rz(7 - i, c, sn);
  }
#pragma unroll
  for (int l = 0; l < 4; ++l) {
#pragma unroll
    for (int i = 0; i < 8; ++i) {
      float aX = qw[l * 16 + i] * 0.5f;
      float cX, sX;
      sincosf(aX, &sX, &cX);
      rx(7 - i, cX, sX);
      float aZ = qw[l * 16 + 8 + i] * 0.5f;
      float cZ, sZ;
      sincosf(aZ, &sZ, &cZ);
      rz(7 - i, cZ, sZ);
    }
#pragma unroll
    for (int i = 0; i < 7; ++i) docnot(i);
  }

  float pr4[4];
#pragma unroll
  for (int l = 0; l < 4; ++l) pr4[l] = sr[l] * sr[l] + si[l] * si[l];
  float z[8];
#pragma unroll
  for (int w = 0; w < 8; ++w) {
    int p = 7 - w;
    float part = 0.f;
#pragma unroll
    for (int l = 0; l < 4; ++l) {
      int bit = (p >= 2) ? ((lane >> (p - 2)) & 1) : ((l >> p) & 1);
      part += bit ? -pr4[l] : pr4[l];
    }
    z[w] = waveAllSum(part);
  }

  float* orow = x2 + row * 512;
  bf16* brow = x2b + row * 512;
#pragma unroll
  for (int j = 0; j < 8; ++j) {
    int col = lane + 64 * j;
    float acc = qout_b[col];
#pragma unroll
    for (int w = 0; w < 8; ++w) acc = fmaf(z[w], qout_w[col * 8 + w], acc);
    float val = xv[j] + acc;
    orow[col] = val;
    brow[col] = (bf16)val;
  }
}

// ---------------------------------------------------------------------------
extern "C" void kernel_launch(void* const* d_in, const int* in_sizes, int n_in,
                              void* d_out, int out_size, void* d_ws,
                              size_t ws_size, hipStream_t stream) {
  const float* x = (const float*)d_in[0];
  const float* attn_in_w = (const float*)d_in[1];
  const float* attn_in_b = (const float*)d_in[2];
  const float* attn_out_w = (const float*)d_in[3];
  const float* attn_out_b = (const float*)d_in[4];
  const float* ln1_g = (const float*)d_in[5];
  const float* ln1_b = (const float*)d_in[6];
  const float* ln2_g = (const float*)d_in[7];
  const float* ln2_b = (const float*)d_in[8];
  const float* ln3_g = (const float*)d_in[9];
  const float* ln3_b = (const float*)d_in[10];
  const float* qin_w = (const float*)d_in[11];
  const float* qin_b = (const float*)d_in[12];
  const float* qweights = (const float*)d_in[13];
  const float* qout_w = (const float*)d_in[14];
  const float* qout_b = (const float*)d_in[15];
  const float* ffn_w1 = (const float*)d_in[16];
  const float* ffn_b1 = (const float*)d_in[17];
  const float* ffn_w2 = (const float*)d_in[18];
  const float* ffn_b2 = (const float*)d_in[19];

  char* wsB = (char*)d_ws;
  bf16* qkb = (bf16*)(wsB);                    // 32 MB  (B,S,1024)
  bf16* vtb = (bf16*)(wsB + (32L << 20));      // 16 MB  (B,H,128,512)
  bf16* ob = (bf16*)(wsB + (48L << 20));       // 16 MB  (B,S,512)
  bf16* hb = (bf16*)(wsB);                     // 64 MB  overlay (qkv dead)
  float* slot1 = (float*)(wsB + (64L << 20));  // 32 MB  attn_out/x1/ffn_out
  float* x2 = (float*)(wsB + (96L << 20));     // 32 MB
  bf16* x2b = (bf16*)(wsB + (128L << 20));     // 16 MB
  bf16* xb = (bf16*)(wsB + (144L << 20));      // 16 MB
  bf16* w_in = (bf16*)(wsB + (160L << 20));    // 1.5 MB
  bf16* w_out = (bf16*)(wsB + (162L << 20));   // 0.5 MB
  bf16* w_f1 = (bf16*)(wsB + (163L << 20));    // 2 MB
  bf16* w_f2 = (bf16*)(wsB + (165L << 20));    // 2 MB

  const int M = 16384;
  float* outp = (float*)d_out;

  // fp32 -> bf16 conversions (every launch; no persistent state allowed)
  cvt_f32_bf16<<<8192, 256, 0, stream>>>(x, xb, 2097152);
  cvt_f32_bf16<<<768, 256, 0, stream>>>(attn_in_w, w_in, 196608);
  cvt_f32_bf16<<<256, 256, 0, stream>>>(attn_out_w, w_out, 65536);
  cvt_f32_bf16<<<1024, 256, 0, stream>>>(ffn_w1, w_f1, 262144);
  cvt_f32_bf16<<<1024, 256, 0, stream>>>(ffn_w2, w_f2, 262144);

  // 1. QKV projection (split epilogue: qk + transposed v)
  gemm_mfma<<<dim3(M / 128, 12), 256, 0, stream>>>(
      xb, w_in, attn_in_b, nullptr, nullptr, qkb, vtb, M, 1536, 512, 2);
  // 2. attention
  attn_mfma<<<dim3(128, 8), 256, 0, stream>>>(qkb, vtb, ob);
  // 3. output projection -> f32
  gemm_mfma<<<dim3(M / 128, 4), 256, 0, stream>>>(
      ob, w_out, attn_out_b, slot1, nullptr, nullptr, nullptr, M, 512, 512, 0);
  // 4. x1 = LN1(x + attn_out) in-place
  add_ln_kernel<<<dim3(M / 4), 256, 0, stream>>>(x, slot1, ln1_g, ln1_b,
                                                 slot1);
  // 5. x2 = x1 + quantum(LN3(x1)); dual write f32 + bf16
  quantum_kernel<<<dim3(M / 4), 256, 0, stream>>>(
      slot1, ln3_g, ln3_b, qin_w, qin_b, qweights, qout_w, qout_b, x2, x2b);
  // 6. h = gelu(x2 @ ffn_w1^T + b1) -> bf16
  gemm_mfma<<<dim3(M / 128, 16), 256, 0, stream>>>(
      x2b, w_f1, ffn_b1, nullptr, hb, nullptr, nullptr, M, 2048, 512, 1);
  // 7. ffn_out = h @ ffn_w2^T + b2 -> f32
  gemm_mfma<<<dim3(M / 128, 4), 256, 0, stream>>>(
      hb, w_f2, ffn_b2, slot1, nullptr, nullptr, nullptr, M, 512, 2048, 0);
  // 8. out = LN2(x2 + ffn_out)
  add_ln_kernel<<<dim3(M / 4), 256, 0, stream>>>(x2, slot1, ln2_g, ln2_b,
                                                 outp);
}

// Round 3
// 503.516 us; speedup vs baseline: 4.7914x; 1.0656x over previous
//
#include <hip/hip_runtime.h>
#include <math.h>

// ---------------------------------------------------------------------------
// QuantumEncoderLayer R3.
//   - gemm_mfma / attn_mfma unchanged from R2 (verified).
//   - quantum_kernel rewritten: fixed-layer RZ*RX gates precomputed once by
//     make_gates (32 general 2x2 complex unitaries read as wave-uniform
//     s_loads); encoding RX+RZ fused into one combined gate (1 sincos/wire);
//     LN1 fused in (wave holds the whole 512-row).
//   - 5 f32->bf16 converts merged into one dispatch.
// ---------------------------------------------------------------------------

typedef __bf16 bf16;
typedef bf16 bf16x8 __attribute__((ext_vector_type(8)));
typedef bf16 bf16x4 __attribute__((ext_vector_type(4)));
typedef float f32x4 __attribute__((ext_vector_type(4)));

__device__ __forceinline__ void gld16(const void* g, void* l) {
  __builtin_amdgcn_global_load_lds(
      (__attribute__((address_space(1))) void*)(void*)g,
      (__attribute__((address_space(3))) void*)l, 16, 0, 0);
}

__device__ __forceinline__ float waveAllSum(float v) {
#pragma unroll
  for (int m = 1; m < 64; m <<= 1) v += __shfl_xor(v, m, 64);
  return v;
}

// ---------------------------------------------------------------------------
// One dispatch converting x + the 4 weight matrices to bf16 (float4 granules).
// Segment sizes in float4 units: x 2097152 | in_w 196608 | out_w 65536 |
// ffn_w1 262144 | ffn_w2 262144.  Total 2883584 -> 11264 blocks.
// ---------------------------------------------------------------------------
__global__ __launch_bounds__(256) void cvt_all(
    const float* __restrict__ x, const float* __restrict__ w1,
    const float* __restrict__ w2, const float* __restrict__ w3,
    const float* __restrict__ w4, bf16* __restrict__ xb,
    bf16* __restrict__ b1, bf16* __restrict__ b2, bf16* __restrict__ b3,
    bf16* __restrict__ b4) {
  int i = blockIdx.x * 256 + threadIdx.x;
  const float* src;
  bf16* dst;
  int off;
  if (i < 2097152) {
    src = x; dst = xb; off = i;
  } else if (i < 2097152 + 196608) {
    src = w1; dst = b1; off = i - 2097152;
  } else if (i < 2097152 + 196608 + 65536) {
    src = w2; dst = b2; off = i - (2097152 + 196608);
  } else if (i < 2097152 + 196608 + 65536 + 262144) {
    src = w3; dst = b3; off = i - (2097152 + 196608 + 65536);
  } else {
    src = w4; dst = b4; off = i - (2097152 + 196608 + 65536 + 262144);
  }
  float4 v = ((const float4*)src)[off];
  bf16x4 o = {(bf16)v.x, (bf16)v.y, (bf16)v.z, (bf16)v.w};
  ((bf16x4*)dst)[off] = o;
}

// ---------------------------------------------------------------------------
// Precompute the 32 fixed layer gates U = RZ(az)*RX(ax) as 8 floats each:
// u00r,u00i,u01r,u01i,u10r,u10i,u11r,u11i.  gate t = layer l (t>>3), wire i.
// ---------------------------------------------------------------------------
__global__ void make_gates(const float* __restrict__ qw,
                           float* __restrict__ gates) {
  int t = threadIdx.x;
  if (t >= 32) return;
  int l = t >> 3, i = t & 7;
  float ax = qw[l * 16 + i] * 0.5f;
  float az = qw[l * 16 + 8 + i] * 0.5f;
  float cx, sx, cz, sz;
  sincosf(ax, &sx, &cx);
  sincosf(az, &sz, &cz);
  float* g = gates + t * 8;
  g[0] = cz * cx;   g[1] = -sz * cx;  // u00
  g[2] = -sz * sx;  g[3] = -cz * sx;  // u01
  g[4] = sz * sx;   g[5] = -cz * sx;  // u10
  g[6] = cz * cx;   g[7] = sz * cx;   // u11
}

// ---------------------------------------------------------------------------
// C[M,N] = A[M,K] @ W[N,K]^T + bias.  (unchanged from R2)
// ---------------------------------------------------------------------------
__global__ __launch_bounds__(256) void gemm_mfma(
    const bf16* __restrict__ A, const bf16* __restrict__ W,
    const float* __restrict__ bias, float* __restrict__ Cf,
    bf16* __restrict__ Cb, bf16* __restrict__ qk, bf16* __restrict__ vT,
    int M, int N, int K, int mode) {
  __shared__ __align__(16) bf16 As[128 * 32];
  __shared__ __align__(16) bf16 Bs[128 * 32];
  int tid = threadIdx.x;
  int lane = tid & 63, w = tid >> 6;
  int wr = w >> 1, wc = w & 1;
  int quad = lane >> 4, lc = lane & 15;
  long m0 = (long)blockIdx.x * 128;
  long n0 = (long)blockIdx.y * 128;
  int r4 = lane >> 2;
  int koff = (lane & 3) * 8;
  f32x4 acc[4][4] = {};

  for (int k0 = 0; k0 < K; k0 += 32) {
    __syncthreads();
#pragma unroll
    for (int p = 0; p < 2; ++p) {
      int row = p * 64 + w * 16 + r4;
      gld16(A + (m0 + row) * (long)K + k0 + koff, &As[row * 32 + koff]);
      gld16(W + (n0 + row) * (long)K + k0 + koff, &Bs[row * 32 + koff]);
    }
    __syncthreads();
    bf16x8 af[4], bfr[4];
#pragma unroll
    for (int i = 0; i < 4; ++i) {
      af[i] = *(const bf16x8*)&As[(wr * 64 + i * 16 + lc) * 32 + quad * 8];
      bfr[i] = *(const bf16x8*)&Bs[(wc * 64 + i * 16 + lc) * 32 + quad * 8];
    }
#pragma unroll
    for (int i = 0; i < 4; ++i)
#pragma unroll
      for (int j = 0; j < 4; ++j)
        acc[i][j] = __builtin_amdgcn_mfma_f32_16x16x32_bf16(af[i], bfr[j],
                                                            acc[i][j], 0, 0, 0);
  }

#pragma unroll
  for (int i = 0; i < 4; ++i) {
    long grow0 = m0 + wr * 64 + i * 16 + quad * 4;
#pragma unroll
    for (int j = 0; j < 4; ++j) {
      long col = n0 + wc * 64 + j * 16 + lc;
      float bv = bias[col];
      float v[4];
#pragma unroll
      for (int r = 0; r < 4; ++r) v[r] = acc[i][j][r] + bv;
      if (mode == 0) {
#pragma unroll
        for (int r = 0; r < 4; ++r) Cf[(grow0 + r) * N + col] = v[r];
      } else if (mode == 1) {
#pragma unroll
        for (int r = 0; r < 4; ++r) {
          float g = 0.5f * v[r] * (1.0f + erff(v[r] * 0.70710678118654752f));
          Cb[(grow0 + r) * N + col] = (bf16)g;
        }
      } else {
        if (col < 1024) {
#pragma unroll
          for (int r = 0; r < 4; ++r) qk[(grow0 + r) * 1024 + col] = (bf16)v[r];
        } else {
          int hh = (int)((col - 1024) >> 7);
          int dd = (int)((col - 1024) & 127);
          long bidx = grow0 >> 9;
          int s0 = (int)(grow0 & 511);
          bf16x4 pk = {(bf16)v[0], (bf16)v[1], (bf16)v[2], (bf16)v[3]};
          *(bf16x4*)&vT[(((bidx << 2) + hh) * 128 + dd) * 512 + s0] = pk;
        }
      }
    }
  }
}

// ---------------------------------------------------------------------------
// Flash attention (unchanged from R2).
// ---------------------------------------------------------------------------
__global__ __launch_bounds__(256) void attn_mfma(const bf16* __restrict__ qk,
                                                 const bf16* __restrict__ vT,
                                                 bf16* __restrict__ o) {
  __shared__ __align__(16) bf16 Ks[64 * 128];
  __shared__ __align__(16) bf16 Vt[128 * 64];
  __shared__ __align__(16) bf16 Ps[4][64 * 16];
  int tid = threadIdx.x, lane = tid & 63, w = tid >> 6;
  int quad = lane >> 4, lc = lane & 15;
  int bh = blockIdx.x, b = bh >> 2, h = bh & 3;
  int q0 = blockIdx.y * 64 + w * 16;
  const float scale = 0.08838834764831845f;

  bf16x8 qf[4];
  {
    const bf16* qp =
        qk + ((long)(b * 512 + q0 + lc)) * 1024 + h * 128 + quad * 8;
#pragma unroll
    for (int ks = 0; ks < 4; ++ks) qf[ks] = *(const bf16x8*)(qp + ks * 32);
  }
  f32x4 oacc[8] = {};
  float mrun[4] = {-1e30f, -1e30f, -1e30f, -1e30f};
  float lrun[4] = {0.f, 0.f, 0.f, 0.f};

  const bf16* kbase = qk + (long)b * 512 * 1024 + 512 + h * 128;
  const bf16* vbase = vT + (long)bh * 128 * 512;
  int kr = lane >> 4, ke = (lane & 15) * 8;
  int vr = lane >> 3, ve = (lane & 7) * 8;

  for (int kt = 0; kt < 512; kt += 64) {
    __syncthreads();
#pragma unroll
    for (int c = 0; c < 4; ++c) {
      int row = w * 16 + c * 4 + kr;
      gld16(kbase + (long)(kt + row) * 1024 + ke, &Ks[row * 128 + ke]);
    }
#pragma unroll
    for (int c = 0; c < 4; ++c) {
      int row = w * 32 + c * 8 + vr;
      gld16(vbase + (long)row * 512 + kt + ve, &Vt[row * 64 + ve]);
    }
    __syncthreads();

    float p[4][4];
#pragma unroll
    for (int c = 0; c < 4; ++c) {
      f32x4 a = {};
#pragma unroll
      for (int ks = 0; ks < 4; ++ks) {
        bf16x8 kf = *(const bf16x8*)&Ks[(c * 16 + lc) * 128 + ks * 32 + quad * 8];
        a = __builtin_amdgcn_mfma_f32_16x16x32_bf16(qf[ks], kf, a, 0, 0, 0);
      }
#pragma unroll
      for (int r = 0; r < 4; ++r) p[c][r] = a[r] * scale;
    }

    float alpha[4];
#pragma unroll
    for (int r = 0; r < 4; ++r) {
      float mx = fmaxf(fmaxf(p[0][r], p[1][r]), fmaxf(p[2][r], p[3][r]));
#pragma unroll
      for (int m = 1; m < 16; m <<= 1) mx = fmaxf(mx, __shfl_xor(mx, m, 64));
      float mn = fmaxf(mrun[r], mx);
      alpha[r] = expf(mrun[r] - mn);
      mrun[r] = mn;
      float rs = 0.f;
#pragma unroll
      for (int c = 0; c < 4; ++c) {
        float e = expf(p[c][r] - mn);
        p[c][r] = e;
        rs += e;
      }
#pragma unroll
      for (int m = 1; m < 16; m <<= 1) rs += __shfl_xor(rs, m, 64);
      lrun[r] = lrun[r] * alpha[r] + rs;
    }
#pragma unroll
    for (int n = 0; n < 8; ++n)
#pragma unroll
      for (int r = 0; r < 4; ++r) oacc[n][r] *= alpha[r];

#pragma unroll
    for (int c = 0; c < 4; ++c) {
      bf16x4 pk = {(bf16)p[c][0], (bf16)p[c][1], (bf16)p[c][2], (bf16)p[c][3]};
      *(bf16x4*)&Ps[w][(c * 16 + lc) * 16 + quad * 4] = pk;
    }
    bf16x8 pf[2];
#pragma unroll
    for (int kc = 0; kc < 2; ++kc) {
      bf16x8 t;
#pragma unroll
      for (int jj = 0; jj < 8; ++jj)
        t[jj] = Ps[w][(kc * 32 + quad * 8 + jj) * 16 + lc];
      pf[kc] = t;
    }
#pragma unroll
    for (int n = 0; n < 8; ++n)
#pragma unroll
      for (int kc = 0; kc < 2; ++kc) {
        bf16x8 vf = *(const bf16x8*)&Vt[(n * 16 + lc) * 64 + kc * 32 + quad * 8];
        oacc[n] =
            __builtin_amdgcn_mfma_f32_16x16x32_bf16(pf[kc], vf, oacc[n], 0, 0, 0);
      }
  }

  float linv[4];
#pragma unroll
  for (int r = 0; r < 4; ++r) linv[r] = 1.0f / lrun[r];
  bf16* op = o + ((long)(b * 512 + q0 + quad * 4)) * 512 + h * 128 + lc;
#pragma unroll
  for (int n = 0; n < 8; ++n)
#pragma unroll
    for (int r = 0; r < 4; ++r)
      op[(long)r * 512 + n * 16] = (bf16)(oacc[n][r] * linv[r]);
}

// ---------------------------------------------------------------------------
__global__ __launch_bounds__(256) void add_ln_kernel(
    const float* __restrict__ a, const float* __restrict__ b,
    const float* __restrict__ g, const float* __restrict__ be,
    float* __restrict__ out) {
  long row = (blockIdx.x * 256 + threadIdx.x) >> 6;
  int lane = threadIdx.x & 63;
  const float* ar = a + row * 512;
  const float* br = b + row * 512;
  float v[8];
  float s = 0.f;
#pragma unroll
  for (int j = 0; j < 8; ++j) {
    int c = lane + 64 * j;
    v[j] = ar[c] + br[c];
    s += v[j];
  }
  s = waveAllSum(s);
  float mean = s * (1.0f / 512.0f);
  float var = 0.f;
#pragma unroll
  for (int j = 0; j < 8; ++j) {
    float d = v[j] - mean;
    var = fmaf(d, d, var);
  }
  var = waveAllSum(var);
  float rstd = rsqrtf(var * (1.0f / 512.0f) + 1e-5f);
  float* orow = out + row * 512;
#pragma unroll
  for (int j = 0; j < 8; ++j) {
    int c = lane + 64 * j;
    orow[c] = (v[j] - mean) * rstd * g[c] + be[c];
  }
}

// ---------------------------------------------------------------------------
// Fused: x1 = LN1(x + attnp); xn = LN3(x1); ang = xn@qin_w^T + qin_b;
// circuit (combined 2x2 gates); z; x2 = x1 + z@qout_w^T + qout_b (f32+bf16).
// State: amp idx = lane*4 + l; wire w <-> bit (7-w); bits 0,1 intra-lane.
// ---------------------------------------------------------------------------
__global__ __launch_bounds__(256) void quantum_kernel(
    const float* __restrict__ x, const float* __restrict__ attnp,
    const float* __restrict__ g1, const float* __restrict__ b1,
    const float* __restrict__ g3, const float* __restrict__ b3,
    const float* __restrict__ qin_w, const float* __restrict__ qin_b,
    const float* __restrict__ gates, const float* __restrict__ qout_w,
    const float* __restrict__ qout_b, float* __restrict__ x2,
    bf16* __restrict__ x2b) {
  long row = (blockIdx.x * 256 + threadIdx.x) >> 6;
  int lane = threadIdx.x & 63;
  const float* xr = x + row * 512;
  const float* ar = attnp + row * 512;

  // LN1(x + attnp) -> x1 (in regs)
  float x1v[8];
  {
    float s = 0.f;
#pragma unroll
    for (int j = 0; j < 8; ++j) {
      int c = lane + 64 * j;
      x1v[j] = xr[c] + ar[c];
      s += x1v[j];
    }
    s = waveAllSum(s);
    float mean = s * (1.0f / 512.0f);
    float var = 0.f;
#pragma unroll
    for (int j = 0; j < 8; ++j) {
      float d = x1v[j] - mean;
      var = fmaf(d, d, var);
    }
    var = waveAllSum(var);
    float rstd = rsqrtf(var * (1.0f / 512.0f) + 1e-5f);
#pragma unroll
    for (int j = 0; j < 8; ++j) {
      int c = lane + 64 * j;
      x1v[j] = (x1v[j] - mean) * rstd * g1[c] + b1[c];
    }
  }

  // LN3(x1) -> xn
  float xn[8];
  {
    float s = 0.f;
#pragma unroll
    for (int j = 0; j < 8; ++j) s += x1v[j];
    s = waveAllSum(s);
    float mean = s * (1.0f / 512.0f);
    float var = 0.f;
#pragma unroll
    for (int j = 0; j < 8; ++j) {
      float d = x1v[j] - mean;
      var = fmaf(d, d, var);
    }
    var = waveAllSum(var);
    float rstd = rsqrtf(var * (1.0f / 512.0f) + 1e-5f);
#pragma unroll
    for (int j = 0; j < 8; ++j) {
      int c = lane + 64 * j;
      xn[j] = (x1v[j] - mean) * rstd * g3[c] + b3[c];
    }
  }

  // angles
  float ang[8];
#pragma unroll
  for (int w = 0; w < 8; ++w) {
    float p = 0.f;
#pragma unroll
    for (int j = 0; j < 8; ++j)
      p = fmaf(xn[j], qin_w[w * 512 + lane + 64 * j], p);
    p = waveAllSum(p);
    ang[w] = p + qin_b[w];
  }

  // state
  float sr[4], si[4];
  sr[0] = (lane == 0) ? 1.0f : 0.0f;
  sr[1] = sr[2] = sr[3] = 0.0f;
  si[0] = si[1] = si[2] = si[3] = 0.0f;

  // general 2x2 complex gate at bit position p
  auto gate = [&](int p, float u00r, float u00i, float u01r, float u01i,
                  float u10r, float u10i, float u11r, float u11i) {
    if (p >= 2) {
      int m = 1 << (p - 2);
      int b = (lane >> (p - 2)) & 1;
      float csr = b ? u11r : u00r;
      float csi = b ? u11i : u00i;
      float cor = b ? u10r : u01r;
      float coi = b ? u10i : u01i;
#pragma unroll
      for (int l = 0; l < 4; ++l) {
        float pr = __shfl_xor(sr[l], m, 64);
        float pi = __shfl_xor(si[l], m, 64);
        float nr = fmaf(csr, sr[l],
                        fmaf(-csi, si[l], fmaf(cor, pr, -coi * pi)));
        float ni = fmaf(csr, si[l],
                        fmaf(csi, sr[l], fmaf(cor, pi, coi * pr)));
        sr[l] = nr;
        si[l] = ni;
      }
    } else {
      float nr[4], ni[4];
#pragma unroll
      for (int l = 0; l < 4; ++l) {
        int b = (l >> p) & 1;  // compile-time after unroll
        int pl = l ^ (1 << p);
        float csr = b ? u11r : u00r;
        float csi = b ? u11i : u00i;
        float cor = b ? u10r : u01r;
        float coi = b ? u10i : u01i;
        nr[l] = fmaf(csr, sr[l],
                     fmaf(-csi, si[l], fmaf(cor, sr[pl], -coi * si[pl])));
        ni[l] = fmaf(csr, si[l],
                     fmaf(csi, sr[l], fmaf(cor, si[pl], coi * sr[pl])));
      }
#pragma unroll
      for (int l = 0; l < 4; ++l) {
        sr[l] = nr[l];
        si[l] = ni[l];
      }
    }
  };

  auto docnot = [&](int i) {
    int pc = 7 - i, pt = 6 - i;
    if (pt >= 2) {
      int ctrl = (lane >> (pc - 2)) & 1;
      int m = 1 << (pt - 2);
#pragma unroll
      for (int l = 0; l < 4; ++l) {
        float pr = __shfl_xor(sr[l], m, 64);
        float pi = __shfl_xor(si[l], m, 64);
        if (ctrl) {
          sr[l] = pr;
          si[l] = pi;
        }
      }
    } else if (pt == 1) {
      if (lane & 1) {
        float t;
        t = sr[0]; sr[0] = sr[2]; sr[2] = t;
        t = si[0]; si[0] = si[2]; si[2] = t;
        t = sr[1]; sr[1] = sr[3]; sr[3] = t;
        t = si[1]; si[1] = si[3]; si[3] = t;
      }
    } else {
      float t;
      t = sr[2]; sr[2] = sr[3]; sr[3] = t;
      t = si[2]; si[2] = si[3]; si[3] = t;
    }
  };

  // encoding: combined RZ(a)*RX(a) per wire (u from c=cos(a/2), s=sin(a/2))
#pragma unroll
  for (int i = 0; i < 8; ++i) {
    float half = ang[i] * 0.5f;
    float c, s;
    sincosf(half, &s, &c);
    float cc = c * c, sc = s * c, ss = s * s;
    gate(7 - i, cc, -sc, -ss, -sc, ss, -sc, cc, sc);
  }
  // layers: precomputed gates + CNOT ladder
#pragma unroll
  for (int l = 0; l < 4; ++l) {
#pragma unroll
    for (int i = 0; i < 8; ++i) {
      const float* g = gates + (l * 8 + i) * 8;
      gate(7 - i, g[0], g[1], g[2], g[3], g[4], g[5], g[6], g[7]);
    }
#pragma unroll
    for (int i = 0; i < 7; ++i) docnot(i);
  }

  // expectation values
  float pr4[4];
#pragma unroll
  for (int l = 0; l < 4; ++l) pr4[l] = sr[l] * sr[l] + si[l] * si[l];
  float z[8];
#pragma unroll
  for (int w = 0; w < 8; ++w) {
    int p = 7 - w;
    float part = 0.f;
#pragma unroll
    for (int l = 0; l < 4; ++l) {
      int bit = (p >= 2) ? ((lane >> (p - 2)) & 1) : ((l >> p) & 1);
      part += bit ? -pr4[l] : pr4[l];
    }
    z[w] = waveAllSum(part);
  }

  // x2 = x1 + z @ qout_w^T + qout_b (dual write)
  float* orow = x2 + row * 512;
  bf16* brow = x2b + row * 512;
#pragma unroll
  for (int j = 0; j < 8; ++j) {
    int col = lane + 64 * j;
    float acc = qout_b[col];
#pragma unroll
    for (int w = 0; w < 8; ++w) acc = fmaf(z[w], qout_w[col * 8 + w], acc);
    float val = x1v[j] + acc;
    orow[col] = val;
    brow[col] = (bf16)val;
  }
}

// ---------------------------------------------------------------------------
extern "C" void kernel_launch(void* const* d_in, const int* in_sizes, int n_in,
                              void* d_out, int out_size, void* d_ws,
                              size_t ws_size, hipStream_t stream) {
  const float* x = (const float*)d_in[0];
  const float* attn_in_w = (const float*)d_in[1];
  const float* attn_in_b = (const float*)d_in[2];
  const float* attn_out_w = (const float*)d_in[3];
  const float* attn_out_b = (const float*)d_in[4];
  const float* ln1_g = (const float*)d_in[5];
  const float* ln1_b = (const float*)d_in[6];
  const float* ln2_g = (const float*)d_in[7];
  const float* ln2_b = (const float*)d_in[8];
  const float* ln3_g = (const float*)d_in[9];
  const float* ln3_b = (const float*)d_in[10];
  const float* qin_w = (const float*)d_in[11];
  const float* qin_b = (const float*)d_in[12];
  const float* qweights = (const float*)d_in[13];
  const float* qout_w = (const float*)d_in[14];
  const float* qout_b = (const float*)d_in[15];
  const float* ffn_w1 = (const float*)d_in[16];
  const float* ffn_b1 = (const float*)d_in[17];
  const float* ffn_w2 = (const float*)d_in[18];
  const float* ffn_b2 = (const float*)d_in[19];

  char* wsB = (char*)d_ws;
  bf16* qkb = (bf16*)(wsB);                    // 32 MB  (B,S,1024)
  bf16* vtb = (bf16*)(wsB + (32L << 20));      // 16 MB  (B,H,128,512)
  bf16* ob = (bf16*)(wsB + (48L << 20));       // 16 MB  (B,S,512)
  bf16* hb = (bf16*)(wsB);                     // 64 MB  overlay (qkv dead)
  float* slot1 = (float*)(wsB + (64L << 20));  // 32 MB  attn_proj / ffn_out
  float* x2 = (float*)(wsB + (96L << 20));     // 32 MB
  bf16* x2b = (bf16*)(wsB + (128L << 20));     // 16 MB
  bf16* xb = (bf16*)(wsB + (144L << 20));      // 16 MB
  bf16* w_in = (bf16*)(wsB + (160L << 20));    // 1.5 MB
  bf16* w_out = (bf16*)(wsB + (162L << 20));   // 0.5 MB
  bf16* w_f1 = (bf16*)(wsB + (163L << 20));    // 2 MB
  bf16* w_f2 = (bf16*)(wsB + (165L << 20));    // 2 MB
  float* gates = (float*)(wsB + (167L << 20)); // 1 KB

  const int M = 16384;
  float* outp = (float*)d_out;

  // converts (one dispatch) + fixed-gate precompute
  cvt_all<<<11264, 256, 0, stream>>>(x, attn_in_w, attn_out_w, ffn_w1, ffn_w2,
                                     xb, w_in, w_out, w_f1, w_f2);
  make_gates<<<1, 64, 0, stream>>>(qweights, gates);

  // 1. QKV projection (split epilogue: qk + transposed v)
  gemm_mfma<<<dim3(M / 128, 12), 256, 0, stream>>>(
      xb, w_in, attn_in_b, nullptr, nullptr, qkb, vtb, M, 1536, 512, 2);
  // 2. attention
  attn_mfma<<<dim3(128, 8), 256, 0, stream>>>(qkb, vtb, ob);
  // 3. output projection -> f32
  gemm_mfma<<<dim3(M / 128, 4), 256, 0, stream>>>(
      ob, w_out, attn_out_b, slot1, nullptr, nullptr, nullptr, M, 512, 512, 0);
  // 4+5. x2 = LN1-fused quantum
  quantum_kernel<<<dim3(M / 4), 256, 0, stream>>>(
      x, slot1, ln1_g, ln1_b, ln3_g, ln3_b, qin_w, qin_b, gates, qout_w,
      qout_b, x2, x2b);
  // 6. h = gelu(x2 @ ffn_w1^T + b1) -> bf16
  gemm_mfma<<<dim3(M / 128, 16), 256, 0, stream>>>(
      x2b, w_f1, ffn_b1, nullptr, hb, nullptr, nullptr, M, 2048, 512, 1);
  // 7. ffn_out = h @ ffn_w2^T + b2 -> f32
  gemm_mfma<<<dim3(M / 128, 4), 256, 0, stream>>>(
      hb, w_f2, ffn_b2, slot1, nullptr, nullptr, nullptr, M, 512, 2048, 0);
  // 8. out = LN2(x2 + ffn_out)
  add_ln_kernel<<<dim3(M / 4), 256, 0, stream>>>(x2, slot1, ln2_g, ln2_b,
                                                 outp);
}